// Round 6
// baseline (366.657 us; speedup 1.0000x reference)
//
#include <hip/hip_runtime.h>

#define I_DIM 16
#define H_DIM 32
#define T_DIM 512
#define B_DIM 4096

__device__ __forceinline__ float fast_tanh(float x) {
    // tanh(x) = 1 - 2/(exp(2x)+1); exp(2x) = exp2(x * 2*log2(e))
    float e = __builtin_amdgcn_exp2f(x * 2.885390081777927f);
    return 1.0f - 2.0f * __builtin_amdgcn_rcpf(e + 1.0f);
}

__device__ __forceinline__ float dot32(const float* __restrict__ w, const float* __restrict__ h) {
    float a0 = 0.f, a1 = 0.f, a2 = 0.f, a3 = 0.f;
#pragma unroll
    for (int k = 0; k < 32; k += 4) {
        a0 = fmaf(w[k+0], h[k+0], a0);
        a1 = fmaf(w[k+1], h[k+1], a1);
        a2 = fmaf(w[k+2], h[k+2], a2);
        a3 = fmaf(w[k+3], h[k+3], a3);
    }
    return (a0 + a1) + (a2 + a3);
}

__global__ void __launch_bounds__(256, 2)
rnn2_fused_kernel(const float* __restrict__ x,
                  const float* __restrict__ Wih0, const float* __restrict__ Whh0,
                  const float* __restrict__ bih0, const float* __restrict__ bhh0,
                  const float* __restrict__ Wih1, const float* __restrict__ Whh1,
                  const float* __restrict__ bih1, const float* __restrict__ bhh1,
                  const float* __restrict__ fcw, const float* __restrict__ fcb,
                  float* __restrict__ out)
{
    const int tid  = threadIdx.x;
    const int j    = tid & 31;        // output row within H
    const int half = tid >> 5;        // 0..7: which batch element of this block
    const int batch = blockIdx.x * 8 + half;

    __shared__ __align__(16) float sh1[8][32];
    __shared__ __align__(16) float sh2[8][32];
    float* sh1p = sh1[half];
    float* sh2p = sh2[half];

    // ---- per-lane weight rows (registers) ----
    float wih0[16], whh0[32], wih1[32], whh1[32];
#pragma unroll
    for (int q = 0; q < 4; ++q) {
        float4 v = reinterpret_cast<const float4*>(Wih0 + j * 16)[q];
        wih0[4*q+0] = v.x; wih0[4*q+1] = v.y; wih0[4*q+2] = v.z; wih0[4*q+3] = v.w;
    }
#pragma unroll
    for (int q = 0; q < 8; ++q) {
        float4 a = reinterpret_cast<const float4*>(Whh0 + j * 32)[q];
        whh0[4*q+0] = a.x; whh0[4*q+1] = a.y; whh0[4*q+2] = a.z; whh0[4*q+3] = a.w;
        float4 b = reinterpret_cast<const float4*>(Wih1 + j * 32)[q];
        wih1[4*q+0] = b.x; wih1[4*q+1] = b.y; wih1[4*q+2] = b.z; wih1[4*q+3] = b.w;
        float4 c = reinterpret_cast<const float4*>(Whh1 + j * 32)[q];
        whh1[4*q+0] = c.x; whh1[4*q+1] = c.y; whh1[4*q+2] = c.z; whh1[4*q+3] = c.w;
    }
    const float bias0 = bih0[j] + bhh0[j];
    const float bias1 = bih1[j] + bhh1[j];

    const float* xrow = x + (size_t)batch * (T_DIM * I_DIM);

    // replicated hidden-state vectors
    float h1v[32], h2v[32];
#pragma unroll
    for (int k = 0; k < 32; ++k) { h1v[k] = 0.f; h2v[k] = 0.f; }

    // xb for t=0
    float xb;
    {
        float xv[16];
#pragma unroll
        for (int q = 0; q < 4; ++q) {
            float4 v = reinterpret_cast<const float4*>(xrow)[q];
            xv[4*q+0] = v.x; xv[4*q+1] = v.y; xv[4*q+2] = v.z; xv[4*q+3] = v.w;
        }
        float a0 = bias0, a1 = 0.f, a2 = 0.f, a3 = 0.f;
#pragma unroll
        for (int d = 0; d < 16; d += 4) {
            a0 = fmaf(wih0[d+0], xv[d+0], a0);
            a1 = fmaf(wih0[d+1], xv[d+1], a1);
            a2 = fmaf(wih0[d+2], xv[d+2], a2);
            a3 = fmaf(wih0[d+3], xv[d+3], a3);
        }
        xb = (a0 + a1) + (a2 + a3);
    }

#pragma unroll 1
    for (int t = 0; t < T_DIM; ++t) {
        // --- prefetch x[t+1] a full iteration ahead ---
        const int tn = (t + 1 < T_DIM) ? (t + 1) : (T_DIM - 1);
        const float4* xp = reinterpret_cast<const float4*>(xrow + tn * I_DIM);
        float4 nx0 = xp[0];
        float4 nx1 = xp[1];
        float4 nx2 = xp[2];
        float4 nx3 = xp[3];

        // --- layer 0: pre = xb + Whh0[j,:] . h1_prev ---
        float pre0 = xb + dot32(whh0, h1v);
        float h1j  = fast_tanh(pre0);
        sh1p[j] = h1j;
        __builtin_amdgcn_wave_barrier();

        // --- layer 1 hh-part with old h2 (overlaps the LDS write latency) ---
        float acc1 = bias1 + dot32(whh1, h2v);

        // --- gather full new h1 vector (broadcast b128 reads) ---
#pragma unroll
        for (int q = 0; q < 8; ++q) {
            float4 v = reinterpret_cast<const float4*>(sh1p)[q];
            h1v[4*q+0] = v.x; h1v[4*q+1] = v.y; h1v[4*q+2] = v.z; h1v[4*q+3] = v.w;
        }

        float pre1 = acc1 + dot32(wih1, h1v);
        float h2j  = fast_tanh(pre1);
        sh2p[j] = h2j;
        __builtin_amdgcn_wave_barrier();

#pragma unroll
        for (int q = 0; q < 8; ++q) {
            float4 v = reinterpret_cast<const float4*>(sh2p)[q];
            h2v[4*q+0] = v.x; h2v[4*q+1] = v.y; h2v[4*q+2] = v.z; h2v[4*q+3] = v.w;
        }

        // --- fold prefetched x into next step's scalar xb ---
        float a0 = bias0, a1 = 0.f, a2 = 0.f, a3 = 0.f;
        a0 = fmaf(wih0[0],  nx0.x, a0); a1 = fmaf(wih0[1],  nx0.y, a1);
        a2 = fmaf(wih0[2],  nx0.z, a2); a3 = fmaf(wih0[3],  nx0.w, a3);
        a0 = fmaf(wih0[4],  nx1.x, a0); a1 = fmaf(wih0[5],  nx1.y, a1);
        a2 = fmaf(wih0[6],  nx1.z, a2); a3 = fmaf(wih0[7],  nx1.w, a3);
        a0 = fmaf(wih0[8],  nx2.x, a0); a1 = fmaf(wih0[9],  nx2.y, a1);
        a2 = fmaf(wih0[10], nx2.z, a2); a3 = fmaf(wih0[11], nx2.w, a3);
        a0 = fmaf(wih0[12], nx3.x, a0); a1 = fmaf(wih0[13], nx3.y, a1);
        a2 = fmaf(wih0[14], nx3.z, a2); a3 = fmaf(wih0[15], nx3.w, a3);
        xb = (a0 + a1) + (a2 + a3);
    }

    // ---- final FC: logits[b] = fc_w . h2_last + fc_b ----
    float fw[32];
#pragma unroll
    for (int q = 0; q < 8; ++q) {
        float4 v = reinterpret_cast<const float4*>(fcw)[q];
        fw[4*q+0] = v.x; fw[4*q+1] = v.y; fw[4*q+2] = v.z; fw[4*q+3] = v.w;
    }
    float logit = fcb[0] + dot32(fw, h2v);
    if (j == 0) out[batch] = logit;
}

extern "C" void kernel_launch(void* const* d_in, const int* in_sizes, int n_in,
                              void* d_out, int out_size, void* d_ws, size_t ws_size,
                              hipStream_t stream) {
    const float* x    = (const float*)d_in[0];
    const float* Wih0 = (const float*)d_in[1];
    const float* Whh0 = (const float*)d_in[2];
    const float* bih0 = (const float*)d_in[3];
    const float* bhh0 = (const float*)d_in[4];
    const float* Wih1 = (const float*)d_in[5];
    const float* Whh1 = (const float*)d_in[6];
    const float* bih1 = (const float*)d_in[7];
    const float* bhh1 = (const float*)d_in[8];
    const float* fcw  = (const float*)d_in[9];
    const float* fcb  = (const float*)d_in[10];
    float* out = (float*)d_out;

    dim3 grid(B_DIM / 8);   // 512 blocks x 256 threads = 4096 half-waves (one per batch row)
    rnn2_fused_kernel<<<grid, 256, 0, stream>>>(x, Wih0, Whh0, bih0, bhh0,
                                                Wih1, Whh1, bih1, bhh1,
                                                fcw, fcb, out);
}